// Round 5
// baseline (198.314 us; speedup 1.0000x reference)
//
#include <hip/hip_runtime.h>
#include <math.h>

#define NN 648      // code length / variables
#define EE 1944     // edges
#define NCHK 324    // checks, each = 6 consecutive edges
#define BATCH 2048
#define BS 256      // extraction kernels
#define BSW 64      // bp_main: ONE WAVE per block, one batch row per block
#define TL_CLAMP 14.508648f   // 2*atanh(0.999999)

// ---------------------------------------------------------------------------
// Fast transcendentals (hardware v_exp_f32 / v_log_f32 / v_rcp_f32).
// CRITICAL: tanh_half returns 0 IFF x==0 — zero-ness gates the reference's
// cn_update nz-mask semantics (exp path flushes |x|<~2e-7 -> Taylor small
// path keeps tiny nonzeros nonzero).
// ---------------------------------------------------------------------------
__device__ __forceinline__ float rcp_fast(float x) { return __builtin_amdgcn_rcpf(x); }

__device__ __forceinline__ float tanh_half(float x) {
    // tanh(x/2) = 1 - 2/(e^x + 1): sign-correct, saturates exactly to +/-1.
    float E = __expf(x);
    float big = 1.0f - 2.0f * rcp_fast(E + 1.0f);
    float u = 0.5f * x;
    float small = u * (1.0f - 0.33333334f * u * u);   // |u|<=2^-6, err ~6e-10
    return (fabsf(x) < 0.03125f) ? small : big;
}

__device__ __forceinline__ float sigm(float s) {
    return rcp_fast(1.0f + __expf(-s));
}

// Two-log CN form: ext = Q/a, 2*atanh(ext) = ln2*(log2|a+Q| - log2|a-Q|),
// clamped at +/-2*atanh(0.999999). a-+Q==0 -> +/-inf -> clamp (== ref clamp).
__device__ __forceinline__ float cn_edge(float a, float Q) {
    float t = 0.6931472f * (__log2f(fabsf(a + Q)) - __log2f(fabsf(a - Q)));
    return fminf(fmaxf(t, -TL_CLAMP), TL_CLAMP);
}

// Rare path (exact-zero member / full underflow): reference skip-zero / any_nz
// extrinsic semantics. By-value args: no pointer to a register array (which
// would force scratch); __noinline__ keeps the hot path lean.
__device__ __noinline__ float cn_fallback(float a, float t0, float t1, float t2,
                                          float t3, float t4, float t5) {
    float vv[6] = {t0, t1, t2, t3, t4, t5};
    float P = 1.0f; int cz = 0;
    #pragma unroll
    for (int k = 0; k < 6; k++) {
        if (vv[k] == 0.0f) cz++; else P *= vv[k];
    }
    float ext;
    if (a != 0.0f) ext = (cz >= 5) ? 0.0f : P * rcp_fast(a);
    else           ext = (cz >= 6) ? 0.0f : P;
    ext = fminf(fmaxf(ext, -0.999999f), 0.999999f);
    return 0.6931472f * __log2f((1.0f + ext) * rcp_fast(1.0f - ext));
}

// ---------------------------------------------------------------------------
// Structure extraction (re-run every call; inputs restored pristine each time)
// M_out is [N,E] = M_ev.T: one nonzero (==1.0) per column e, at row var_of[e].
// Each var appears once per permutation layer (layer = e/NN) -> race-free.
// ---------------------------------------------------------------------------
__global__ __launch_bounds__(BS) void extract_struct(
    const float4* __restrict__ M_out4,
    int* __restrict__ var_of, int* __restrict__ varEdge) {
    int t = blockIdx.x * BS + threadIdx.x;
    if (t >= NN * EE / 4) return;
    float4 v = M_out4[t];
    int flat = t * 4;
    int n = flat / EE;
    int e = flat - n * EE;
    if (v.x != 0.0f) { var_of[e]     = n; varEdge[n*3 + (e)    /NN] = e;     }
    if (v.y != 0.0f) { var_of[e + 1] = n; varEdge[n*3 + (e + 1)/NN] = e + 1; }
    if (v.z != 0.0f) { var_of[e + 2] = n; varEdge[n*3 + (e + 2)/NN] = e + 2; }
    if (v.w != 0.0f) { var_of[e + 3] = n; varEdge[n*3 + (e + 3)/NN] = e + 3; }
}

// One thread per (matrix, edge): 2 scalar loads each, plus NN threads for W9.
// Weight layout per CHECK: 12 floats (2 per edge) = 3 float4 (float2-index == e,
// edges are check-consecutive). w0 pairs the LOWER-slot neighbor, w1 the higher
// (ea,eb ascend in slot order) — matches bp_main's derived (kA,kB) rule.
// vnb[e] = 4*var_of[e] + slot(e), slot = e/NN: the var-major LDS address.
__global__ __launch_bounds__(BS) void extract_weights(
    const float* __restrict__ W1, const float* __restrict__ W3,
    const float* __restrict__ W5, const float* __restrict__ W7,
    const float* __restrict__ W9,
    const int* __restrict__ var_of, const int* __restrict__ varEdge,
    unsigned* __restrict__ vnb,
    float4* __restrict__ w1q, float4* __restrict__ w3q,
    float4* __restrict__ w5q, float4* __restrict__ w7q,
    float* __restrict__ w9v) {
    int t = blockIdx.x * BS + threadIdx.x;
    if (t < 4 * EE) {
        int m = t / EE;
        int e = t - m * EE;
        int n = var_of[e];
        int e0 = varEdge[3 * n], e1 = varEdge[3 * n + 1], e2 = varEdge[3 * n + 2];
        int ea, eb;
        if (e == e0)      { ea = e1; eb = e2; }   // own slot 0 -> neighbors (1,2)
        else if (e == e1) { ea = e0; eb = e2; }   // own slot 1 -> neighbors (0,2)
        else              { ea = e0; eb = e1; }   // own slot 2 -> neighbors (0,1)
        const float* W = (m == 0) ? W1 : (m == 1) ? W3 : (m == 2) ? W5 : W7;
        size_t row = (size_t)e * EE;
        float2 w = make_float2(W[row + ea], W[row + eb]);
        float4* dq = (m == 0) ? w1q : (m == 1) ? w3q : (m == 2) ? w5q : w7q;
        ((float2*)dq)[e] = w;
        if (m == 0) vnb[e] = (unsigned)(4 * n + e / NN);
    } else if (t < 4 * EE + NN) {
        int n = t - 4 * EE;
        #pragma unroll
        for (int k = 0; k < 3; k++) {
            int e = varEdge[3 * n + k];
            w9v[3 * n + k] = W9[(size_t)n * EE + e];   // slot-k ordered
        }
    }
}

// ---------------------------------------------------------------------------
// Main BP kernel, R5 structure: ONE WAVE (64 threads) per block, ONE batch row
// per block. Each lane owns 5-6 checks (324 = 5*64+4); all 36 edge states
// (te, vb) live in registers.
// Why (R2/R4 post-mortem): three structurally different multi-wave versions
// all pinned at ~137us with every pipe 97% idle -> latency/serialization of
// the 6-wave barrier chain at ~5 blocks/CU, not LDS banking. Single-wave
// blocks make __syncthreads ~free (s_barrier with 1 wave is immediately
// satisfied), give 6x per-lane ILP on the exp/log chains, and 12 blocks/CU
// (LDS 12.96 KB) with grid 2048 = 0.67 rounds.
// tlv layout: float tlv[4*v+k], k=slot 0..2, pad at 3 -> ONE ds_read_b128
// serves both the VN gather and marg. Single-buffered: per stage,
// phase1 = ALL VN reads -> sync -> phase2 = ALL CN writes -> sync.
// ---------------------------------------------------------------------------
__global__ __launch_bounds__(BSW, 3) void bp_main(
    const float* __restrict__ x,
    const unsigned* __restrict__ vnb_g,  // uint[EE]: 4*var + slot
    const float4* __restrict__ w1q, const float4* __restrict__ w3q,
    const float4* __restrict__ w5q, const float4* __restrict__ w7q,
    const float* __restrict__ w9v,
    float* __restrict__ out) {
    __shared__ float llr_s[NN];
    __shared__ __align__(16) float tlv[4 * NN];   // [4v+k], pad at k=3
    const int b = blockIdx.x;
    const int lane = threadIdx.x;

    for (int i = lane; i < NN; i += BSW)
        llr_s[i] = x[(size_t)b * NN + i];
    __syncthreads();

    unsigned vb[36];   // 4*v+k per owned edge — persistent registers
    float te[36];      // tanh'd VN outputs per owned edge — registers

    // stage 0: te = tanh(0.5*llr[var]); also load vb once (reused all stages)
    #pragma unroll
    for (int k = 0; k < 6; k++) {
        int c = lane + 64 * k;
        if (c < NCHK) {
            #pragma unroll
            for (int j = 0; j < 6; j++) {
                unsigned a = vnb_g[6 * c + j];
                vb[6 * k + j] = a;
                te[6 * k + j] = tanh_half(llr_s[a >> 2]);
            }
        }
    }

    auto cn_all = [&]() {   // CN for all owned checks: scattered b32 writes
        #pragma unroll
        for (int k = 0; k < 6; k++) {
            int c = lane + 64 * k;
            if (c < NCHK) {
                float Q = ((te[6*k] * te[6*k+1]) * (te[6*k+2] * te[6*k+3]))
                        * (te[6*k+4] * te[6*k+5]);
                if (__builtin_expect(Q != 0.0f, 1)) {
                    #pragma unroll
                    for (int j = 0; j < 6; j++)
                        tlv[vb[6*k+j]] = cn_edge(te[6*k+j], Q);
                } else {
                    #pragma unroll
                    for (int j = 0; j < 6; j++)
                        tlv[vb[6*k+j]] = cn_fallback(te[6*k+j],
                            te[6*k], te[6*k+1], te[6*k+2],
                            te[6*k+3], te[6*k+4], te[6*k+5]);
                }
            }
        }
    };
    auto marg = [&](float* dst) {   // one b128 per var, lanes consecutive
        #pragma unroll
        for (int i = 0; i < 11; i++) {
            int n = lane + 64 * i;
            if (n < NN) {
                float4 q = *(const float4*)&tlv[4 * n];   // k0,k1,k2,pad
                dst[n] = sigm(llr_s[n] + (q.x + q.y) + q.z);
            }
        }
    };

    cn_all();            // CN stage 0
    __syncthreads();
    // out1 -> chunk 4 (return order: out5,out4,out3,out2,out1)
    marg(out + ((size_t)(4 * BATCH) + b) * NN);

    #pragma unroll 1
    for (int t = 1; t <= 4; t++) {
        const float4* __restrict__ wq =
            (t == 1) ? w1q : (t == 2) ? w3q : (t == 3) ? w5q : w7q;
        // phase 1: VN for all owned checks (reads CN_{t-1} from tlv)
        #pragma unroll
        for (int k = 0; k < 6; k++) {
            int c = lane + 64 * k;
            if (c < NCHK) {
                float4 wa = wq[3 * c], wbv = wq[3 * c + 1], wcv = wq[3 * c + 2];
                float w[12] = {wa.x, wa.y, wa.z, wa.w, wbv.x, wbv.y, wbv.z, wbv.w,
                               wcv.x, wcv.y, wcv.z, wcv.w};
                #pragma unroll
                for (int j = 0; j < 6; j++) {
                    unsigned a = vb[6 * k + j];
                    int kk = a & 3;
                    float4 q = *(const float4*)&tlv[a & ~3u];  // k0,k1,k2,pad
                    float cA = (kk == 0) ? q.y : q.x;   // kA = (k==0)?1:0
                    float cB = (kk == 2) ? q.y : q.z;   // kB = (k==2)?1:2
                    float lb = llr_s[a >> 2];
                    te[6*k+j] = tanh_half(fmaf(w[2*j], cA, fmaf(w[2*j+1], cB, lb)));
                }
            }
        }
        __syncthreads();   // all reads of CN_{t-1} done (marg_{t-1} was earlier)
        cn_all();          // phase 2: CN_t overwrites tlv
        __syncthreads();   // CN_t visible
        if (t < 4) {
            // out2->chunk3, out3->chunk2, out4->chunk1
            marg(out + ((size_t)((4 - t) * BATCH) + b) * NN);
        } else {
            // out5 -> chunk 0: sigmoid(t@W9.T + llr)   (B4 = I)
            #pragma unroll
            for (int i = 0; i < 11; i++) {
                int n = lane + 64 * i;
                if (n < NN) {
                    float4 q = *(const float4*)&tlv[4 * n];
                    float s = llr_s[n] + w9v[3*n] * q.x + w9v[3*n+1] * q.y
                                       + w9v[3*n+2] * q.z;
                    out[(size_t)b * NN + n] = sigm(s);
                }
            }
        }
    }
}

// ---------------------------------------------------------------------------
extern "C" void kernel_launch(void* const* d_in, const int* in_sizes, int n_in,
                              void* d_out, int out_size, void* d_ws, size_t ws_size,
                              hipStream_t stream) {
    const float* x     = (const float*)d_in[0];
    const float* M_out = (const float*)d_in[3];
    const float* W1    = (const float*)d_in[5];
    const float* W3    = (const float*)d_in[6];
    const float* W5    = (const float*)d_in[7];
    const float* W7    = (const float*)d_in[8];
    const float* W9    = (const float*)d_in[9];
    // d_in[1]=M_first, d_in[2]=M_cn (patterns implied by check structure),
    // d_in[4]=bias_matrix (values 1.0), d_in[10..14]=B0..B4 (identity).
    float* out = (float*)d_out;

    char* ws = (char*)d_ws;                    // 16B-aligned base
    float4* w1q     = (float4*)ws;         ws += (EE / 2) * 16;
    float4* w3q     = (float4*)ws;         ws += (EE / 2) * 16;
    float4* w5q     = (float4*)ws;         ws += (EE / 2) * 16;
    float4* w7q     = (float4*)ws;         ws += (EE / 2) * 16;
    int*    var_of  = (int*)ws;            ws += EE * 4;
    int*    varEdge = (int*)ws;            ws += NN * 3 * 4;
    float*  w9v     = (float*)ws;          ws += NN * 3 * 4;
    unsigned* vnb   = (unsigned*)ws;       ws += EE * 4;

    const int tot4 = NN * EE / 4;
    extract_struct<<<(tot4 + BS - 1) / BS, BS, 0, stream>>>(
        (const float4*)M_out, var_of, varEdge);
    const int totW = 4 * EE + NN;
    extract_weights<<<(totW + BS - 1) / BS, BS, 0, stream>>>(
        W1, W3, W5, W7, W9, var_of, varEdge, vnb, w1q, w3q, w5q, w7q, w9v);
    bp_main<<<BATCH, BSW, 0, stream>>>(
        x, vnb, w1q, w3q, w5q, w7q, w9v, out);
}

// Round 6
// 167.332 us; speedup vs baseline: 1.1851x; 1.1851x over previous
//
#include <hip/hip_runtime.h>
#include <math.h>

#define NN 648      // code length / variables
#define EE 1944     // edges
#define NCHK 324    // checks, each = 6 consecutive edges
#define BATCH 2048
#define BSX 256     // extraction kernel (4 waves = 4 vars per block)
#define BSM 384     // bp_main: one check per thread (324 < 384), 6 waves
#define ROWS 2      // batch rows per block (row-interleaved in LDS)
#define TL_CLAMP 14.508648f   // 2*atanh(0.999999)

// ---------------------------------------------------------------------------
// Fast transcendentals (hardware v_exp_f32 / v_log_f32 / v_rcp_f32).
// CRITICAL: tanh_half returns 0 IFF x==0 — zero-ness gates the reference's
// cn_update nz-mask semantics (exp path flushes |x|<~2e-7 -> Taylor small
// path keeps tiny nonzeros nonzero).
// ---------------------------------------------------------------------------
__device__ __forceinline__ float rcp_fast(float x) { return __builtin_amdgcn_rcpf(x); }

__device__ __forceinline__ float tanh_half(float x) {
    // tanh(x/2) = 1 - 2/(e^x + 1): sign-correct, saturates exactly to +/-1.
    float E = __expf(x);
    float big = 1.0f - 2.0f * rcp_fast(E + 1.0f);
    float u = 0.5f * x;
    float small = u * (1.0f - 0.33333334f * u * u);   // |u|<=2^-6, err ~6e-10
    return (fabsf(x) < 0.03125f) ? small : big;
}

__device__ __forceinline__ float sigm(float s) {
    return rcp_fast(1.0f + __expf(-s));
}

// Two-log CN form: ext = Q/a, 2*atanh(ext) = ln2*(log2|a+Q| - log2|a-Q|),
// clamped at +/-2*atanh(0.999999). a-+Q==0 -> +/-inf -> clamp (== ref clamp).
__device__ __forceinline__ float cn_edge(float a, float Q) {
    float t = 0.6931472f * (__log2f(fabsf(a + Q)) - __log2f(fabsf(a - Q)));
    return fminf(fmaxf(t, -TL_CLAMP), TL_CLAMP);
}

// Rare path (exact-zero member / full underflow): reference skip-zero / any_nz
// extrinsic semantics. By-value args: no pointer to a register array (which
// would force scratch); __noinline__ keeps the hot path lean.
__device__ __noinline__ float cn_fallback(float a, float t0, float t1, float t2,
                                          float t3, float t4, float t5) {
    float vv[6] = {t0, t1, t2, t3, t4, t5};
    float P = 1.0f; int cz = 0;
    #pragma unroll
    for (int k = 0; k < 6; k++) {
        if (vv[k] == 0.0f) cz++; else P *= vv[k];
    }
    float ext;
    if (a != 0.0f) ext = (cz >= 5) ? 0.0f : P * rcp_fast(a);
    else           ext = (cz >= 6) ? 0.0f : P;
    ext = fminf(fmaxf(ext, -0.999999f), 0.999999f);
    return 0.6931472f * __log2f((1.0f + ext) * rcp_fast(1.0f - ext));
}

// ---------------------------------------------------------------------------
// R6: SINGLE merged extraction kernel. One WAVE per variable n: scan row n of
// M_out (1944 floats, coalesced float4) to find its 3 edges (one per layer,
// layer = e/NN, e ascending across layers), then directly emit:
//   vnb[e]  = 4*n + slot(e)                         (bp_main LDS address)
//   wXq     : per-edge float2 {w_lowerslot, w_higherslot} from W1/3/5/7
//   w9v[3n+k] = W9[n, e_k]
// Replaces the old 2-kernel extract chain (removes a launch + the
// var_of/varEdge intermediates). 162 blocks x 4 waves cover 648 vars.
// ---------------------------------------------------------------------------
__global__ __launch_bounds__(BSX) void extract_all(
    const float4* __restrict__ M_out4,
    const float* __restrict__ W1, const float* __restrict__ W3,
    const float* __restrict__ W5, const float* __restrict__ W7,
    const float* __restrict__ W9,
    unsigned* __restrict__ vnb,
    float* __restrict__ w1f, float* __restrict__ w3f,
    float* __restrict__ w5f, float* __restrict__ w7f,
    float* __restrict__ w9v) {
    const int wave = threadIdx.x >> 6;
    const int lane = threadIdx.x & 63;
    const int n = blockIdx.x * (BSX / 64) + wave;
    __shared__ int varE[BSX / 64][3];

    if (n < NN) {
        const float4* row = M_out4 + (size_t)n * (EE / 4);
        #pragma unroll
        for (int it = 0; it < 8; it++) {
            int idx = lane + 64 * it;
            if (idx < EE / 4) {
                float4 v = row[idx];
                int e = idx * 4;
                // each float4 holds at most one nonzero (vars unique per layer,
                // layers are float4-aligned: 648 = 162*4)
                if (v.x != 0.0f) varE[wave][(e    ) / NN] = e;
                if (v.y != 0.0f) varE[wave][(e + 1) / NN] = e + 1;
                if (v.z != 0.0f) varE[wave][(e + 2) / NN] = e + 2;
                if (v.w != 0.0f) varE[wave][(e + 3) / NN] = e + 3;
            }
        }
    }
    __syncthreads();
    if (n >= NN) return;
    const int e0 = varE[wave][0], e1 = varE[wave][1], e2 = varE[wave][2];

    if (lane < 24) {
        // lanes 0..23: 4 matrices x 6 (edge, neighbor) weight loads
        int m = lane / 6, idx = lane % 6;
        int k = idx >> 1;                                  // own slot
        int ek = (k == 0) ? e0 : (k == 1) ? e1 : e2;
        int lo, hi;                                        // other two, ascending
        if (k == 0)      { lo = e1; hi = e2; }
        else if (k == 1) { lo = e0; hi = e2; }
        else             { lo = e0; hi = e1; }
        int eo = (idx & 1) ? hi : lo;
        const float* W = (m == 0) ? W1 : (m == 1) ? W3 : (m == 2) ? W5 : W7;
        float v = W[(size_t)ek * EE + eo];
        float* dst = (m == 0) ? w1f : (m == 1) ? w3f : (m == 2) ? w5f : w7f;
        dst[2 * ek + (idx & 1)] = v;                       // float2-per-edge layout
    } else if (lane < 27) {
        int k = lane - 24;
        int ek = (k == 0) ? e0 : (k == 1) ? e1 : e2;
        w9v[3 * n + k] = W9[(size_t)n * EE + ek];
    } else if (lane == 27) {
        vnb[e0] = 4u * n + 0; vnb[e1] = 4u * n + 1; vnb[e2] = 4u * n + 2;
    }
}

// ---------------------------------------------------------------------------
// Main BP kernel = R4 structure (best measured steady state ~31us) + register
// prefetch. CN outputs VAR-MAJOR + ROW-INTERLEAVED in LDS:
// tlv[4*v + k] = float2{row0,row1}, k = slot 0..2 (pad at k=3).
//   - VN gather  = 1 b128 + 1 b64 per member, serving BOTH rows
//   - marg       = 1 b128 + 1 b64 per var, consecutive lanes
//   - only scatter: 6 b64 CN writes per check
// R6 additions (theory: per-stage 48B/thread weight loads serialize at stage
// start; prefetch one stage ahead so the L2 latency spans cn_store + 2
// barriers + marg):
//   - stage s+1 weights loaded during stage s compute
//   - W9 epilogue operands + marg llr loaded before the last barriers
//   - __launch_bounds__(384,6): old (384,8) capped VGPR at 64; prefetch needs
//     ~+18 regs. 6 waves/EU -> 24 waves/CU = 4 blocks/CU, grid 1024 = exactly
//     one round at 4 blocks/CU. LDS 25.9 KB.
// ---------------------------------------------------------------------------
__global__ __launch_bounds__(BSM, 6) void bp_main(
    const float* __restrict__ x,
    const unsigned* __restrict__ vnb_g,  // uint[EE]: 4*var + slot
    const float4* __restrict__ w1q, const float4* __restrict__ w3q,
    const float4* __restrict__ w5q, const float4* __restrict__ w7q,
    const float* __restrict__ w9v,
    float* __restrict__ out) {
    __shared__ __align__(16) float2 llr2[NN];      // {row0,row1} llr
    __shared__ __align__(16) float2 tlv[4 * NN];   // [4v+k] = {row0,row1}
    const int b0 = blockIdx.x * ROWS;
    const int tid = threadIdx.x;

    {   // llr load, row-interleaved: two coalesced streams
        const float* x0 = x + (size_t)b0 * NN;
        for (int i = tid; i < NN; i += BSM)
            llr2[i] = make_float2(x0[i], x0[NN + i]);
    }
    __syncthreads();

    const bool ck = tid < NCHK;
    const int c = tid;
    float lb0[6], lb1[6];   // llr at this check's 6 member vars, both rows
    float te0[6], te1[6];   // tanh'd VN outputs (check members) — registers
    unsigned vb[6];         // 4*v + k per member

    if (ck) {
        #pragma unroll
        for (int j = 0; j < 6; j++) {
            vb[j] = vnb_g[6 * c + j];
            float2 l = llr2[vb[j] >> 2];
            lb0[j] = l.x; lb1[j] = l.y;
            te0[j] = tanh_half(lb0[j]);   // stage 0: te = tanh(0.5*llr[var])
            te1[j] = tanh_half(lb1[j]);
        }
    }
    // marg-role constants: own llr pair, kept in regs (reused 5x + epilogue)
    float2 lm[2];
    #pragma unroll
    for (int j = 0; j < 2; j++) {
        int n = tid + j * BSM;
        lm[j] = (n < NN) ? llr2[n] : make_float2(0.f, 0.f);
    }
    // prefetch stage-1 weights NOW: latency spans cn_store + barrier + marg
    float4 wA, wB, wC;
    if (ck) { wA = w1q[3 * c]; wB = w1q[3 * c + 1]; wC = w1q[3 * c + 2]; }

    auto cn_store = [&]() {   // 6 scattered b64 writes (the one scatter/layer)
        float Q0 = ((te0[0]*te0[1])*(te0[2]*te0[3]))*(te0[4]*te0[5]);
        float Q1 = ((te1[0]*te1[1])*(te1[2]*te1[3]))*(te1[4]*te1[5]);
        if (__builtin_expect((Q0 != 0.0f) & (Q1 != 0.0f), 1)) {
            #pragma unroll
            for (int j = 0; j < 6; j++)
                tlv[vb[j]] = make_float2(cn_edge(te0[j], Q0),
                                         cn_edge(te1[j], Q1));
        } else {
            #pragma unroll
            for (int j = 0; j < 6; j++) {
                float r0 = (Q0 != 0.0f) ? cn_edge(te0[j], Q0)
                    : cn_fallback(te0[j], te0[0], te0[1], te0[2], te0[3], te0[4], te0[5]);
                float r1 = (Q1 != 0.0f) ? cn_edge(te1[j], Q1)
                    : cn_fallback(te1[j], te1[0], te1[1], te1[2], te1[3], te1[4], te1[5]);
                tlv[vb[j]] = make_float2(r0, r1);
            }
        }
    };
    auto marg = [&](float* dst) {   // wide, consecutive-lane reads
        #pragma unroll
        for (int j = 0; j < 2; j++) {
            int n = tid + j * BSM;
            if (n < NN) {
                float4 q = *(const float4*)&tlv[4 * n];  // {r0k0,r1k0,r0k1,r1k1}
                float2 p = tlv[4 * n + 2];               // {r0k2,r1k2}
                dst[n]      = sigm(lm[j].x + (q.x + q.z) + p.x);
                dst[NN + n] = sigm(lm[j].y + (q.y + q.w) + p.y);
            }
        }
    };

    if (ck) cn_store();          // CN stage 0
    __syncthreads();
    // out1 -> chunk 4 (return order: out5,out4,out3,out2,out1)
    marg(out + ((size_t)(4 * BATCH) + b0) * NN);

    const float4* wqs[4] = {w1q, w3q, w5q, w7q};
    float u0[2], u1[2], u2[2];   // W9 epilogue operands (prefetched at s==3)
    #pragma unroll
    for (int s = 0; s < 4; s++) {
        if (ck) {
            float4 a = wA, bq = wB, cq = wC;       // this stage's weights
            if (s < 3) {                           // prefetch next stage
                const float4* nx = wqs[s + 1];
                wA = nx[3 * c]; wB = nx[3 * c + 1]; wC = nx[3 * c + 2];
            }
            float w[12] = {a.x, a.y, a.z, a.w, bq.x, bq.y, bq.z, bq.w,
                           cq.x, cq.y, cq.z, cq.w};
            // VN: pre = w0*tl[neighbor kA] + w1*tl[neighbor kB] + llr[var]
            // kA,kB = ascending other-two of own slot k (matches extraction).
            #pragma unroll
            for (int j = 0; j < 6; j++) {
                unsigned ad = vb[j];
                int k = ad & 3;
                const float2* basep = &tlv[ad & ~3u];
                float4 q = *(const float4*)basep;        // {r0k0,r1k0,r0k1,r1k1}
                float2 p = basep[2];                     // {r0k2,r1k2}
                float cA0 = (k == 0) ? q.z : q.x;        // kA = (k==0)?1:0
                float cA1 = (k == 0) ? q.w : q.y;
                float cB0 = (k == 2) ? q.z : p.x;        // kB = (k==2)?1:2
                float cB1 = (k == 2) ? q.w : p.y;
                te0[j] = tanh_half(fmaf(w[2*j], cA0, fmaf(w[2*j+1], cB0, lb0[j])));
                te1[j] = tanh_half(fmaf(w[2*j], cA1, fmaf(w[2*j+1], cB1, lb1[j])));
            }
        }
        if (s == 3) {   // prefetch W9 rows: latency spans 2 barriers + cn_store
            #pragma unroll
            for (int j = 0; j < 2; j++) {
                int n = tid + j * BSM;
                if (n < NN) {
                    u0[j] = w9v[3 * n]; u1[j] = w9v[3 * n + 1];
                    u2[j] = w9v[3 * n + 2];
                }
            }
        }
        __syncthreads();          // all tlv reads (marg + VN) of stage s done
        if (ck) cn_store();       // CN stage s+1 overwrites tlv
        __syncthreads();          // stage s+1 visible
        if (s < 3) {
            // out2->chunk3, out3->chunk2, out4->chunk1
            marg(out + ((size_t)((3 - s) * BATCH) + b0) * NN);
        } else {
            // out5 -> chunk 0: sigmoid(t@W9.T + llr)   (B4 = I)
            #pragma unroll
            for (int j2 = 0; j2 < 2; j2++) {
                int n = tid + j2 * BSM;
                if (n < NN) {
                    float4 q = *(const float4*)&tlv[4 * n];
                    float2 p = tlv[4 * n + 2];
                    out[(size_t)b0 * NN + n] =
                        sigm(lm[j2].x + u0[j2]*q.x + u1[j2]*q.z + u2[j2]*p.x);
                    out[((size_t)b0 + 1) * NN + n] =
                        sigm(lm[j2].y + u0[j2]*q.y + u1[j2]*q.w + u2[j2]*p.y);
                }
            }
        }
    }
}

// ---------------------------------------------------------------------------
extern "C" void kernel_launch(void* const* d_in, const int* in_sizes, int n_in,
                              void* d_out, int out_size, void* d_ws, size_t ws_size,
                              hipStream_t stream) {
    const float* x     = (const float*)d_in[0];
    const float* M_out = (const float*)d_in[3];
    const float* W1    = (const float*)d_in[5];
    const float* W3    = (const float*)d_in[6];
    const float* W5    = (const float*)d_in[7];
    const float* W7    = (const float*)d_in[8];
    const float* W9    = (const float*)d_in[9];
    // d_in[1]=M_first, d_in[2]=M_cn (patterns implied by check structure),
    // d_in[4]=bias_matrix (values 1.0), d_in[10..14]=B0..B4 (identity).
    float* out = (float*)d_out;

    char* ws = (char*)d_ws;                    // 16B-aligned base
    float4* w1q     = (float4*)ws;         ws += (EE / 2) * 16;
    float4* w3q     = (float4*)ws;         ws += (EE / 2) * 16;
    float4* w5q     = (float4*)ws;         ws += (EE / 2) * 16;
    float4* w7q     = (float4*)ws;         ws += (EE / 2) * 16;
    float*  w9v     = (float*)ws;          ws += NN * 3 * 4;
    unsigned* vnb   = (unsigned*)ws;       ws += EE * 4;

    extract_all<<<(NN + 3) / 4, BSX, 0, stream>>>(
        (const float4*)M_out, W1, W3, W5, W7, W9, vnb,
        (float*)w1q, (float*)w3q, (float*)w5q, (float*)w7q, w9v);
    bp_main<<<BATCH / ROWS, BSM, 0, stream>>>(
        x, vnb, w1q, w3q, w5q, w7q, w9v, out);
}